// Round 1
// baseline (94.495 us; speedup 1.0000x reference)
//
#include <hip/hip_runtime.h>
#include <hip/hip_bf16.h>
#include <math.h>

namespace {
constexpr int B = 4;
constexpr int S = 4096;
constexpr int H = 2048;
constexpr int DR = 3;          // depth
constexpr int KSEL = 1365;     // int(4096/3)
constexpr int NBLK1 = 1024;    // blocks in score kernel
}

// ---------------------------------------------------------------------------
// K1: raw[d][t] = dot(hidden[t,:], w[d,:]); sc = sigmoid(raw) (exp-form, f32);
//     store float bits of sc0 as sortable keys; accumulate per-block partial
//     sums of sigmoid(sc_d) for the balancing loss (deterministic).
// ---------------------------------------------------------------------------
__global__ __launch_bounds__(256) void ecr_scores(const float* __restrict__ hid,
                                                  const float* __restrict__ w,
                                                  unsigned* __restrict__ keys,
                                                  float* __restrict__ partials) {
    __shared__ float wl[DR * H];        // 24 KB
    __shared__ float s2l[4][DR];
    const float4* wg4 = reinterpret_cast<const float4*>(w);
    float4* wl4 = reinterpret_cast<float4*>(wl);
    for (int i = threadIdx.x; i < DR * H / 4; i += 256) wl4[i] = wg4[i];
    __syncthreads();

    const int wave = threadIdx.x >> 6;
    const int lane = threadIdx.x & 63;
    const int gwave = blockIdx.x * 4 + wave;          // 0..4095
    const float4* wl4_0 = reinterpret_cast<const float4*>(wl);
    const float4* wl4_1 = wl4_0 + (H / 4);
    const float4* wl4_2 = wl4_0 + 2 * (H / 4);

    float part0 = 0.f, part1 = 0.f, part2 = 0.f;

    for (int it = 0; it < (B * S) / 4096; ++it) {     // 4 tokens per wave
        const int t = gwave + it * 4096;              // flat token = b*S+s
        const float4* h4 = reinterpret_cast<const float4*>(hid) + (size_t)t * (H / 4);
        float a0 = 0.f, a1 = 0.f, a2 = 0.f;
#pragma unroll
        for (int j = 0; j < H / 256; ++j) {           // 8 float4 per lane
            const int idx = j * 64 + lane;
            const float4 hv = h4[idx];
            const float4 w0 = wl4_0[idx];
            const float4 w1 = wl4_1[idx];
            const float4 w2 = wl4_2[idx];
            a0 = fmaf(hv.x, w0.x, a0); a0 = fmaf(hv.y, w0.y, a0);
            a0 = fmaf(hv.z, w0.z, a0); a0 = fmaf(hv.w, w0.w, a0);
            a1 = fmaf(hv.x, w1.x, a1); a1 = fmaf(hv.y, w1.y, a1);
            a1 = fmaf(hv.z, w1.z, a1); a1 = fmaf(hv.w, w1.w, a1);
            a2 = fmaf(hv.x, w2.x, a2); a2 = fmaf(hv.y, w2.y, a2);
            a2 = fmaf(hv.z, w2.z, a2); a2 = fmaf(hv.w, w2.w, a2);
        }
#pragma unroll
        for (int off = 32; off >= 1; off >>= 1) {     // 64-lane butterfly
            a0 += __shfl_xor(a0, off);
            a1 += __shfl_xor(a1, off);
            a2 += __shfl_xor(a2, off);
        }
        if (lane == 0) {
            const float sc0 = 1.0f / (1.0f + expf(-a0));
            const float sc1 = 1.0f / (1.0f + expf(-a1));
            const float sc2 = 1.0f / (1.0f + expf(-a2));
            keys[t] = __float_as_uint(sc0);           // sc0 in [0,1] -> monotone bits
            part0 += 1.0f / (1.0f + expf(-sc0));
            part1 += 1.0f / (1.0f + expf(-sc1));
            part2 += 1.0f / (1.0f + expf(-sc2));
        }
    }
    if (lane == 0) { s2l[wave][0] = part0; s2l[wave][1] = part1; s2l[wave][2] = part2; }
    __syncthreads();
    if (threadIdx.x == 0) {
        float p0 = 0.f, p1 = 0.f, p2 = 0.f;
        for (int v = 0; v < 4; ++v) { p0 += s2l[v][0]; p1 += s2l[v][1]; p2 += s2l[v][2]; }
        partials[blockIdx.x * 3 + 0] = p0;
        partials[blockIdx.x * 3 + 1] = p1;
        partials[blockIdx.x * 3 + 2] = p2;
    }
}

// ---------------------------------------------------------------------------
// K2: per-batch exact top-KSEL with jax tie-break (value desc, index asc).
//     Radix-select (4x 8-bit digits, MSB first) finds the k-th largest key
//     v*, then m = #ties to take, chosen by lowest index via bitmask
//     prefix-popcount. Writes depth assignments and all three masks.
// ---------------------------------------------------------------------------
__global__ __launch_bounds__(512) void ecr_select(const unsigned* __restrict__ keys,
                                                  float* __restrict__ out) {
    __shared__ unsigned kl[S];          // 16 KB
    __shared__ int bins[256];
    __shared__ unsigned bm[S / 32];     // tie bitmask
    __shared__ unsigned sh_prefix;
    __shared__ int sh_krem;

    const int b = blockIdx.x;
    for (int s = threadIdx.x; s < S; s += 512) kl[s] = keys[b * S + s];
    if (threadIdx.x == 0) { sh_prefix = 0u; sh_krem = KSEL; }
    __syncthreads();

    for (int pass = 0; pass < 4; ++pass) {
        const int shift = 24 - pass * 8;
        for (int i = threadIdx.x; i < 256; i += 512) bins[i] = 0;
        __syncthreads();
        const unsigned pref = sh_prefix;
        const int krem = sh_krem;
        const unsigned himask = (pass == 0) ? 0u : (0xFFFFFFFFu << (shift + 8));
        for (int s = threadIdx.x; s < S; s += 512) {
            const unsigned key = kl[s];
            if ((key & himask) == (pref & himask))
                atomicAdd(&bins[(key >> shift) & 255], 1);
        }
        __syncthreads();
        if (threadIdx.x == 0) {
            int cum = 0, dig = 255;
            for (; dig > 0; --dig) {
                if (cum + bins[dig] >= krem) break;
                cum += bins[dig];
            }
            sh_prefix = pref | ((unsigned)dig << shift);
            sh_krem = krem - cum;
        }
        __syncthreads();
    }
    const unsigned vstar = sh_prefix;
    const int m = sh_krem;              // take m lowest-index ties at vstar

    for (int i = threadIdx.x; i < S / 32; i += 512) bm[i] = 0u;
    __syncthreads();
    for (int s = threadIdx.x; s < S; s += 512)
        if (kl[s] == vstar) atomicOr(&bm[s >> 5], 1u << (s & 31));
    __syncthreads();

    float* depth = out;                       // [B*S]
    float* masks = out + B * S + 1;           // [DR][B*S]
    for (int s = threadIdx.x; s < S; s += 512) {
        const unsigned key = kl[s];
        int sel;
        if (key > vstar) sel = 1;
        else if (key < vstar) sel = 0;
        else {
            int rank = 0;
            const int wd = s >> 5;
            for (int i = 0; i < wd; ++i) rank += __popc(bm[i]);
            rank += __popc(bm[wd] & ((1u << (s & 31)) - 1u));
            sel = (rank < m) ? 1 : 0;
        }
        const float fsel = sel ? 1.0f : 0.0f;
        depth[b * S + s] = sel ? 3.0f : 1.0f;
        masks[0 * B * S + b * S + s] = 1.0f;
        masks[1 * B * S + b * S + s] = fsel;
        masks[2 * B * S + b * S + s] = fsel;
    }
}

// ---------------------------------------------------------------------------
// K3: deterministic reduction of partials -> probs -> KL balancing loss.
// ---------------------------------------------------------------------------
__global__ __launch_bounds__(256) void ecr_loss(const float* __restrict__ partials,
                                                float* __restrict__ out) {
    __shared__ double red[3][256];
    double a0 = 0.0, a1 = 0.0, a2 = 0.0;
    for (int i = threadIdx.x; i < NBLK1; i += 256) {
        a0 += (double)partials[i * 3 + 0];
        a1 += (double)partials[i * 3 + 1];
        a2 += (double)partials[i * 3 + 2];
    }
    red[0][threadIdx.x] = a0; red[1][threadIdx.x] = a1; red[2][threadIdx.x] = a2;
    __syncthreads();
    if (threadIdx.x == 0) {
        double s0 = 0.0, s1 = 0.0, s2 = 0.0;
        for (int i = 0; i < 256; ++i) { s0 += red[0][i]; s1 += red[1][i]; s2 += red[2][i]; }
        const double n = (double)(B * S);
        const double p0 = s0 / n, p1 = s1 / n, p2 = s2 / n;
        const double lt = log(1.0 / 3.0);
        double l = (lt - log(p0)) + (lt - log(p1)) + (lt - log(p2));
        l = l * (1.0 / 3.0) / 3.0;
        out[B * S] = (float)l;
    }
}

extern "C" void kernel_launch(void* const* d_in, const int* in_sizes, int n_in,
                              void* d_out, int out_size, void* d_ws, size_t ws_size,
                              hipStream_t stream) {
    const float* hid = (const float*)d_in[0];     // [B,S,H] f32
    const float* w   = (const float*)d_in[1];     // [DR,H] f32
    float* out = (float*)d_out;                   // depth[B*S] | loss | masks[DR*B*S]

    unsigned* keys  = (unsigned*)d_ws;                                  // B*S uint
    float* partials = (float*)((char*)d_ws + (size_t)B * S * sizeof(unsigned)); // NBLK1*3

    ecr_scores<<<NBLK1, 256, 0, stream>>>(hid, w, keys, partials);
    ecr_select<<<B, 512, 0, stream>>>(keys, out);
    ecr_loss<<<1, 256, 0, stream>>>(partials, out);
}

// Round 2
// 45.667 us; speedup vs baseline: 2.0692x; 2.0692x over previous
//
#include <hip/hip_runtime.h>
#include <hip/hip_bf16.h>
#include <math.h>

namespace {
constexpr int B = 4;
constexpr int S = 4096;
constexpr int H = 2048;
constexpr int DR = 3;          // depth
constexpr int KSEL = 1365;     // int(4096/3)
constexpr int NBLK1 = 1024;    // blocks in score kernel
}

// ---------------------------------------------------------------------------
// K1: raw[d][t] = dot(hidden[t,:], w[d,:]); sc = sigmoid(raw) (exp-form, f32);
//     store float bits of sc0 as sortable keys; accumulate per-block partial
//     sums of sigmoid(sc_d) for the balancing loss (deterministic).
// ---------------------------------------------------------------------------
__global__ __launch_bounds__(256) void ecr_scores(const float* __restrict__ hid,
                                                  const float* __restrict__ w,
                                                  unsigned* __restrict__ keys,
                                                  float* __restrict__ partials) {
    __shared__ float wl[DR * H];        // 24 KB
    __shared__ float s2l[4][DR];
    const float4* wg4 = reinterpret_cast<const float4*>(w);
    float4* wl4 = reinterpret_cast<float4*>(wl);
    for (int i = threadIdx.x; i < DR * H / 4; i += 256) wl4[i] = wg4[i];
    __syncthreads();

    const int wave = threadIdx.x >> 6;
    const int lane = threadIdx.x & 63;
    const int gwave = blockIdx.x * 4 + wave;          // 0..4095
    const float4* wl4_0 = reinterpret_cast<const float4*>(wl);
    const float4* wl4_1 = wl4_0 + (H / 4);
    const float4* wl4_2 = wl4_0 + 2 * (H / 4);

    float part0 = 0.f, part1 = 0.f, part2 = 0.f;

    for (int it = 0; it < (B * S) / 4096; ++it) {     // 4 tokens per wave
        const int t = gwave + it * 4096;              // flat token = b*S+s
        const float4* h4 = reinterpret_cast<const float4*>(hid) + (size_t)t * (H / 4);
        float a0 = 0.f, a1 = 0.f, a2 = 0.f;
#pragma unroll
        for (int j = 0; j < H / 256; ++j) {           // 8 float4 per lane
            const int idx = j * 64 + lane;
            const float4 hv = h4[idx];
            const float4 w0 = wl4_0[idx];
            const float4 w1 = wl4_1[idx];
            const float4 w2 = wl4_2[idx];
            a0 = fmaf(hv.x, w0.x, a0); a0 = fmaf(hv.y, w0.y, a0);
            a0 = fmaf(hv.z, w0.z, a0); a0 = fmaf(hv.w, w0.w, a0);
            a1 = fmaf(hv.x, w1.x, a1); a1 = fmaf(hv.y, w1.y, a1);
            a1 = fmaf(hv.z, w1.z, a1); a1 = fmaf(hv.w, w1.w, a1);
            a2 = fmaf(hv.x, w2.x, a2); a2 = fmaf(hv.y, w2.y, a2);
            a2 = fmaf(hv.z, w2.z, a2); a2 = fmaf(hv.w, w2.w, a2);
        }
#pragma unroll
        for (int off = 32; off >= 1; off >>= 1) {     // 64-lane butterfly
            a0 += __shfl_xor(a0, off);
            a1 += __shfl_xor(a1, off);
            a2 += __shfl_xor(a2, off);
        }
        if (lane == 0) {
            const float sc0 = 1.0f / (1.0f + expf(-a0));
            const float sc1 = 1.0f / (1.0f + expf(-a1));
            const float sc2 = 1.0f / (1.0f + expf(-a2));
            keys[t] = __float_as_uint(sc0);           // sc0 in [0,1] -> monotone bits
            part0 += 1.0f / (1.0f + expf(-sc0));
            part1 += 1.0f / (1.0f + expf(-sc1));
            part2 += 1.0f / (1.0f + expf(-sc2));
        }
    }
    if (lane == 0) { s2l[wave][0] = part0; s2l[wave][1] = part1; s2l[wave][2] = part2; }
    __syncthreads();
    if (threadIdx.x == 0) {
        float p0 = 0.f, p1 = 0.f, p2 = 0.f;
        for (int v = 0; v < 4; ++v) { p0 += s2l[v][0]; p1 += s2l[v][1]; p2 += s2l[v][2]; }
        partials[blockIdx.x * 3 + 0] = p0;
        partials[blockIdx.x * 3 + 1] = p1;
        partials[blockIdx.x * 3 + 2] = p2;
    }
}

// ---------------------------------------------------------------------------
// K2: per-batch exact top-KSEL (value desc, index asc) via branch-uniform
//     bitwise binary search on the key bits (no atomics, no serial scans).
//     Keys live in registers: thread t owns indices [t*8, t*8+8) so local
//     order == global index order (stable tie handling).
//     Block 0 additionally reduces the loss partials (fused ecr_loss).
// ---------------------------------------------------------------------------
__global__ __launch_bounds__(512) void ecr_select(const unsigned* __restrict__ keys,
                                                  const float* __restrict__ partials,
                                                  float* __restrict__ out) {
    const int b = blockIdx.x;
    const int t = threadIdx.x;
    const int wave = t >> 6;
    const int lane = t & 63;

    __shared__ int wsum[8];

    // each thread holds 8 consecutive keys in registers
    const uint4* kp = reinterpret_cast<const uint4*>(keys + b * S + t * 8);
    const uint4 ka = kp[0], kb = kp[1];
    unsigned kr[8] = {ka.x, ka.y, ka.z, ka.w, kb.x, kb.y, kb.z, kb.w};

    // ---- binary search for v* = KSEL-th largest key (keys <= 0x3F800000) ----
    unsigned v = 0;
    for (int bit = 29; bit >= 0; --bit) {
        const unsigned cand = v | (1u << bit);
        int c = 0;
#pragma unroll
        for (int i = 0; i < 8; ++i) c += (kr[i] >= cand);
#pragma unroll
        for (int off = 32; off >= 1; off >>= 1) c += __shfl_xor(c, off);
        if (lane == 0) wsum[wave] = c;
        __syncthreads();
        int tot = 0;
#pragma unroll
        for (int w = 0; w < 8; ++w) tot += wsum[w];
        if (tot >= KSEL) v = cand;                    // uniform decision
        __syncthreads();
    }
    const unsigned vstar = v;

    // ---- g = #{key > v*};  m = KSEL - g ties accepted (lowest index) ----
    int c = 0;
#pragma unroll
    for (int i = 0; i < 8; ++i) c += (kr[i] > vstar);
#pragma unroll
    for (int off = 32; off >= 1; off >>= 1) c += __shfl_xor(c, off);
    if (lane == 0) wsum[wave] = c;
    __syncthreads();
    int g = 0;
#pragma unroll
    for (int w = 0; w < 8; ++w) g += wsum[w];
    const int m = KSEL - g;
    __syncthreads();

    // ---- stable tie rank via prefix scan of per-thread tie counts ----
    int tc = 0;
#pragma unroll
    for (int i = 0; i < 8; ++i) tc += (kr[i] == vstar);
    int sc = tc;                                      // inclusive wave scan
#pragma unroll
    for (int off = 1; off <= 32; off <<= 1) {
        const int o = __shfl_up(sc, off);
        if (lane >= off) sc += o;
    }
    if (lane == 63) wsum[wave] = sc;                  // wave totals
    __syncthreads();
    int wbase = 0;
    for (int w = 0; w < wave; ++w) wbase += wsum[w];
    int rank = wbase + (sc - tc);                     // rank of this thread's first tie

    // ---- emit depth + masks ----
    float dep[8], f1[8];
#pragma unroll
    for (int i = 0; i < 8; ++i) {
        int sel;
        if (kr[i] > vstar) sel = 1;
        else if (kr[i] == vstar) { sel = (rank < m) ? 1 : 0; ++rank; }
        else sel = 0;
        dep[i] = sel ? 3.0f : 1.0f;
        f1[i] = sel ? 1.0f : 0.0f;
    }
    float* depth = out;                               // [B*S]
    float* masks = out + B * S + 1;                   // [DR][B*S], base misaligned -> scalar stores
    float4* dp4 = reinterpret_cast<float4*>(depth + b * S + t * 8);
    dp4[0] = make_float4(dep[0], dep[1], dep[2], dep[3]);
    dp4[1] = make_float4(dep[4], dep[5], dep[6], dep[7]);
    const int mb = b * S + t * 8;
#pragma unroll
    for (int i = 0; i < 8; ++i) {
        masks[0 * B * S + mb + i] = 1.0f;
        masks[1 * B * S + mb + i] = f1[i];
        masks[2 * B * S + mb + i] = f1[i];
    }

    // ---- block 0: fused balancing-loss reduction ----
    if (b == 0) {
        __shared__ double red[3][8];
        double a0 = 0.0, a1 = 0.0, a2 = 0.0;
        for (int i = t; i < NBLK1; i += 512) {
            a0 += (double)partials[i * 3 + 0];
            a1 += (double)partials[i * 3 + 1];
            a2 += (double)partials[i * 3 + 2];
        }
#pragma unroll
        for (int off = 32; off >= 1; off >>= 1) {
            a0 += __shfl_xor(a0, off);
            a1 += __shfl_xor(a1, off);
            a2 += __shfl_xor(a2, off);
        }
        if (lane == 0) { red[0][wave] = a0; red[1][wave] = a1; red[2][wave] = a2; }
        __syncthreads();
        if (t == 0) {
            double s0 = 0.0, s1 = 0.0, s2 = 0.0;
#pragma unroll
            for (int w = 0; w < 8; ++w) { s0 += red[0][w]; s1 += red[1][w]; s2 += red[2][w]; }
            const double n = (double)(B * S);
            const double lt = log(1.0 / 3.0);
            double l = (lt - log(s0 / n)) + (lt - log(s1 / n)) + (lt - log(s2 / n));
            out[B * S] = (float)(l * (1.0 / 3.0) / 3.0);
        }
    }
}

extern "C" void kernel_launch(void* const* d_in, const int* in_sizes, int n_in,
                              void* d_out, int out_size, void* d_ws, size_t ws_size,
                              hipStream_t stream) {
    const float* hid = (const float*)d_in[0];     // [B,S,H] f32
    const float* w   = (const float*)d_in[1];     // [DR,H] f32
    float* out = (float*)d_out;                   // depth[B*S] | loss | masks[DR*B*S]

    unsigned* keys  = (unsigned*)d_ws;                                  // B*S uint
    float* partials = (float*)((char*)d_ws + (size_t)B * S * sizeof(unsigned)); // NBLK1*3

    ecr_scores<<<NBLK1, 256, 0, stream>>>(hid, w, keys, partials);
    ecr_select<<<B, 512, 0, stream>>>(keys, partials, out);
}

// Round 3
// 35.956 us; speedup vs baseline: 2.6281x; 1.2701x over previous
//
#include <hip/hip_runtime.h>
#include <hip/hip_bf16.h>
#include <math.h>

namespace {
constexpr int B = 4;
constexpr int S = 4096;
constexpr int H = 2048;
constexpr int DR = 3;          // depth
constexpr int KSEL = 1365;     // int(4096/3)
constexpr int NBLK1 = 2048;    // blocks in score kernel
constexpr unsigned FONE = 0x3F800000u;  // bits of 1.0f
}

// ---------------------------------------------------------------------------
// K1: raw[d][t] = dot(hidden[t,:], w[d,:]); sc = sigmoid(raw) (exp-form, f32);
//     keys = float bits of sc0 (monotone in [0,1]); per-block partial sums of
//     sigmoid(sc_d) for the loss. 2 tokens per wave, interleaved for MLP.
// ---------------------------------------------------------------------------
__global__ __launch_bounds__(256) void ecr_scores(const float* __restrict__ hid,
                                                  const float* __restrict__ w,
                                                  unsigned* __restrict__ keys,
                                                  float* __restrict__ partials) {
    __shared__ float wl[DR * H];        // 24 KB
    __shared__ float s2l[4][DR];
    const float4* wg4 = reinterpret_cast<const float4*>(w);
    float4* wl4 = reinterpret_cast<float4*>(wl);
    for (int i = threadIdx.x; i < DR * H / 4; i += 256) wl4[i] = wg4[i];
    __syncthreads();

    const int wave = threadIdx.x >> 6;
    const int lane = threadIdx.x & 63;
    const int gw = blockIdx.x * 4 + wave;             // 0..8191
    const int t0 = gw * 2;                            // flat token = b*S+s
    const float4* wl4_0 = reinterpret_cast<const float4*>(wl);
    const float4* wl4_1 = wl4_0 + (H / 4);
    const float4* wl4_2 = wl4_0 + 2 * (H / 4);
    const float4* h40 = reinterpret_cast<const float4*>(hid) + (size_t)t0 * (H / 4);
    const float4* h41 = h40 + (H / 4);

    float a00 = 0.f, a01 = 0.f, a02 = 0.f;            // token 0, depths 0..2
    float a10 = 0.f, a11 = 0.f, a12 = 0.f;            // token 1
#pragma unroll
    for (int j = 0; j < H / 256; ++j) {               // 8 iters, 2x float4/lane
        const int idx = j * 64 + lane;
        const float4 hv0 = h40[idx];
        const float4 hv1 = h41[idx];
        const float4 w0 = wl4_0[idx];
        const float4 w1 = wl4_1[idx];
        const float4 w2 = wl4_2[idx];
        a00 = fmaf(hv0.x, w0.x, a00); a10 = fmaf(hv1.x, w0.x, a10);
        a00 = fmaf(hv0.y, w0.y, a00); a10 = fmaf(hv1.y, w0.y, a10);
        a00 = fmaf(hv0.z, w0.z, a00); a10 = fmaf(hv1.z, w0.z, a10);
        a00 = fmaf(hv0.w, w0.w, a00); a10 = fmaf(hv1.w, w0.w, a10);
        a01 = fmaf(hv0.x, w1.x, a01); a11 = fmaf(hv1.x, w1.x, a11);
        a01 = fmaf(hv0.y, w1.y, a01); a11 = fmaf(hv1.y, w1.y, a11);
        a01 = fmaf(hv0.z, w1.z, a01); a11 = fmaf(hv1.z, w1.z, a11);
        a01 = fmaf(hv0.w, w1.w, a01); a11 = fmaf(hv1.w, w1.w, a11);
        a02 = fmaf(hv0.x, w2.x, a02); a12 = fmaf(hv1.x, w2.x, a12);
        a02 = fmaf(hv0.y, w2.y, a02); a12 = fmaf(hv1.y, w2.y, a12);
        a02 = fmaf(hv0.z, w2.z, a02); a12 = fmaf(hv1.z, w2.z, a12);
        a02 = fmaf(hv0.w, w2.w, a02); a12 = fmaf(hv1.w, w2.w, a12);
    }
#pragma unroll
    for (int off = 32; off >= 1; off >>= 1) {         // 64-lane butterfly x6
        a00 += __shfl_xor(a00, off); a01 += __shfl_xor(a01, off);
        a02 += __shfl_xor(a02, off); a10 += __shfl_xor(a10, off);
        a11 += __shfl_xor(a11, off); a12 += __shfl_xor(a12, off);
    }
    float part0 = 0.f, part1 = 0.f, part2 = 0.f;
    if (lane == 0) {
        const float s00 = 1.0f / (1.0f + expf(-a00));
        const float s01 = 1.0f / (1.0f + expf(-a01));
        const float s02 = 1.0f / (1.0f + expf(-a02));
        const float s10 = 1.0f / (1.0f + expf(-a10));
        const float s11 = 1.0f / (1.0f + expf(-a11));
        const float s12 = 1.0f / (1.0f + expf(-a12));
        keys[t0] = __float_as_uint(s00);
        keys[t0 + 1] = __float_as_uint(s10);
        part0 = 1.0f / (1.0f + expf(-s00)) + 1.0f / (1.0f + expf(-s10));
        part1 = 1.0f / (1.0f + expf(-s01)) + 1.0f / (1.0f + expf(-s11));
        part2 = 1.0f / (1.0f + expf(-s02)) + 1.0f / (1.0f + expf(-s12));
        s2l[wave][0] = part0; s2l[wave][1] = part1; s2l[wave][2] = part2;
    }
    __syncthreads();
    if (threadIdx.x == 0) {
        float p0 = 0.f, p1 = 0.f, p2 = 0.f;
#pragma unroll
        for (int v = 0; v < 4; ++v) { p0 += s2l[v][0]; p1 += s2l[v][1]; p2 += s2l[v][2]; }
        partials[blockIdx.x * 3 + 0] = p0;
        partials[blockIdx.x * 3 + 1] = p1;
        partials[blockIdx.x * 3 + 2] = p2;
    }
}

// ---------------------------------------------------------------------------
// K2: per-batch exact top-KSEL (value desc, index asc). Fast path: if
//     count(key == 1.0f) >= KSEL (true for saturated sigmoid data), v*=1.0f
//     immediately; else branch-uniform bitwise binary search (1 barrier/iter,
//     double-buffered). Stable tie rank via shuffle prefix scan. Block 0
//     fuses the balancing-loss reduction.
// ---------------------------------------------------------------------------
__global__ __launch_bounds__(512) void ecr_select(const unsigned* __restrict__ keys,
                                                  const float* __restrict__ partials,
                                                  float* __restrict__ out) {
    const int b = blockIdx.x;
    const int t = threadIdx.x;
    const int wave = t >> 6;
    const int lane = t & 63;

    __shared__ int wsum[2][8];
    __shared__ int wscan[8];

    // each thread holds 8 consecutive keys in registers (index order preserved)
    const uint4* kp = reinterpret_cast<const uint4*>(keys + b * S + t * 8);
    const uint4 ka = kp[0], kb = kp[1];
    unsigned kr[8] = {ka.x, ka.y, ka.z, ka.w, kb.x, kb.y, kb.z, kb.w};

    // ---- fast path probe: count keys == 1.0f ----
    int c = 0;
#pragma unroll
    for (int i = 0; i < 8; ++i) c += (kr[i] == FONE);
#pragma unroll
    for (int off = 32; off >= 1; off >>= 1) c += __shfl_xor(c, off);
    if (lane == 0) wsum[0][wave] = c;
    __syncthreads();
    int tot1 = 0;
#pragma unroll
    for (int w = 0; w < 8; ++w) tot1 += wsum[0][w];

    unsigned vstar;
    int m;                                            // ties accepted (lowest index)
    if (tot1 >= KSEL) {                               // block-uniform decision
        vstar = FONE;                                 // nothing can exceed 1.0f
        m = KSEL;
    } else {
        // ---- general bitwise binary search, 1 barrier per iteration ----
        unsigned v = 0;
        int pb = 1;                                   // wsum[0] just consumed
        for (int bit = 29; bit >= 0; --bit) {
            const unsigned cand = v | (1u << bit);
            int cc = 0;
#pragma unroll
            for (int i = 0; i < 8; ++i) cc += (kr[i] >= cand);
#pragma unroll
            for (int off = 32; off >= 1; off >>= 1) cc += __shfl_xor(cc, off);
            if (lane == 0) wsum[pb][wave] = cc;
            __syncthreads();
            int tot = 0;
#pragma unroll
            for (int w = 0; w < 8; ++w) tot += wsum[pb][w];
            if (tot >= KSEL) v = cand;
            pb ^= 1;
        }
        vstar = v;
        // g = #{key > v*}
        int cg = 0;
#pragma unroll
        for (int i = 0; i < 8; ++i) cg += (kr[i] > vstar);
#pragma unroll
        for (int off = 32; off >= 1; off >>= 1) cg += __shfl_xor(cg, off);
        if (lane == 0) wsum[pb][wave] = cg;
        __syncthreads();
        int g = 0;
#pragma unroll
        for (int w = 0; w < 8; ++w) g += wsum[pb][w];
        m = KSEL - g;
    }

    // ---- stable tie rank via prefix scan of per-thread tie counts ----
    int tc = 0;
#pragma unroll
    for (int i = 0; i < 8; ++i) tc += (kr[i] == vstar);
    int sc = tc;                                      // inclusive wave scan
#pragma unroll
    for (int off = 1; off <= 32; off <<= 1) {
        const int o = __shfl_up(sc, off);
        if (lane >= off) sc += o;
    }
    if (lane == 63) wscan[wave] = sc;                 // wave totals
    __syncthreads();
    int wbase = 0;
    for (int w = 0; w < wave; ++w) wbase += wscan[w];
    int rank = wbase + (sc - tc);                     // rank of this thread's first tie

    // ---- emit depth + masks ----
    float dep[8], f1[8];
#pragma unroll
    for (int i = 0; i < 8; ++i) {
        int sel;
        if (kr[i] > vstar) sel = 1;
        else if (kr[i] == vstar) { sel = (rank < m) ? 1 : 0; ++rank; }
        else sel = 0;
        dep[i] = sel ? 3.0f : 1.0f;
        f1[i] = sel ? 1.0f : 0.0f;
    }
    float* depth = out;                               // [B*S]
    float* masks = out + B * S + 1;                   // [DR][B*S] (base misaligned)
    float4* dp4 = reinterpret_cast<float4*>(depth + b * S + t * 8);
    dp4[0] = make_float4(dep[0], dep[1], dep[2], dep[3]);
    dp4[1] = make_float4(dep[4], dep[5], dep[6], dep[7]);
    const int mb = b * S + t * 8;
#pragma unroll
    for (int i = 0; i < 8; ++i) {
        masks[0 * B * S + mb + i] = 1.0f;
        masks[1 * B * S + mb + i] = f1[i];
        masks[2 * B * S + mb + i] = f1[i];
    }

    // ---- block 0: fused balancing-loss reduction ----
    if (b == 0) {
        __shared__ double red[3][8];
        double a0 = 0.0, a1 = 0.0, a2 = 0.0;
        for (int i = t; i < NBLK1; i += 512) {
            a0 += (double)partials[i * 3 + 0];
            a1 += (double)partials[i * 3 + 1];
            a2 += (double)partials[i * 3 + 2];
        }
#pragma unroll
        for (int off = 32; off >= 1; off >>= 1) {
            a0 += __shfl_xor(a0, off);
            a1 += __shfl_xor(a1, off);
            a2 += __shfl_xor(a2, off);
        }
        if (lane == 0) { red[0][wave] = a0; red[1][wave] = a1; red[2][wave] = a2; }
        __syncthreads();
        if (t == 0) {
            double s0 = 0.0, s1 = 0.0, s2 = 0.0;
#pragma unroll
            for (int w = 0; w < 8; ++w) { s0 += red[0][w]; s1 += red[1][w]; s2 += red[2][w]; }
            const double n = (double)(B * S);
            const double lt = log(1.0 / 3.0);
            double l = (lt - log(s0 / n)) + (lt - log(s1 / n)) + (lt - log(s2 / n));
            out[B * S] = (float)(l * (1.0 / 3.0) / 3.0);
        }
    }
}

extern "C" void kernel_launch(void* const* d_in, const int* in_sizes, int n_in,
                              void* d_out, int out_size, void* d_ws, size_t ws_size,
                              hipStream_t stream) {
    const float* hid = (const float*)d_in[0];     // [B,S,H] f32
    const float* w   = (const float*)d_in[1];     // [DR,H] f32
    float* out = (float*)d_out;                   // depth[B*S] | loss | masks[DR*B*S]

    unsigned* keys  = (unsigned*)d_ws;                                  // B*S uint
    float* partials = (float*)((char*)d_ws + (size_t)B * S * sizeof(unsigned)); // NBLK1*3

    ecr_scores<<<NBLK1, 256, 0, stream>>>(hid, w, keys, partials);
    ecr_select<<<B, 512, 0, stream>>>(keys, partials, out);
}